// Round 6
// baseline (54.077 us; speedup 1.0000x reference)
//
#include <hip/hip_runtime.h>

// ContrastiveLoss on MI355X — symmetric Gram, BARRIER-FREE wave-private
// staging. Each wave stages its own 64-row A-half + 64-row B-half into a
// private LDS region (2 x 8KB double buffer), syncs only via per-wave
// counted vmcnt(8). No s_barrier / __syncthreads in the K loop: 8 waves/CU
// free-run, hiding each other's L2 latency (m114 co-scheduling).
// Upper triangle only (528 tiles of 128x128, class-uniform): neg tiles
// accumulate row+col exp-sums/maxes; pos tiles dump dots, compared +
// finalized in pos_fin_k.
//
// Swizzle (rule #21): global_load_lds writes linearly, so the 16B-chunk
// permutation is applied on the GLOBAL source (chunk = (lane&3) ^
// ((lane>>3)&3), i.e. slot ^ ((row>>1)&3)) and the SAME XOR on the ds_read
// side (slot = fh ^ ((fr>>1)&3)). Per 16-lane read phase this spreads rows
// across all 8 bank-quads exactly 2x -> 2-way = free (m136).

#define KGRP 8
#define FD   512
#define N1T  2048
#define NT   4096
#define TEMPW 0.02f

typedef __attribute__((ext_vector_type(8))) short short8;
typedef __attribute__((ext_vector_type(4))) float f32x4;
typedef unsigned short ushort_t;

// ---- helpers ---------------------------------------------------------------

// order-preserving float<->uint encoding for atomicMax on floats
__device__ __forceinline__ unsigned enc_ord(float f) {
  unsigned u = __float_as_uint(f);
  return (u & 0x80000000u) ? ~u : (u | 0x80000000u);
}
__device__ __forceinline__ float dec_ord(unsigned u) {
  unsigned b = (u & 0x80000000u) ? (u & 0x7fffffffu) : ~u;
  return __uint_as_float(b);
}

// f32 -> bf16 round-to-nearest-even (bit trick)
__device__ __forceinline__ ushort_t f2bf(float f) {
  unsigned u = __float_as_uint(f);
  u = (u + 0x7fffu + ((u >> 16) & 1u)) >> 16;
  return (ushort_t)u;
}

// async global->LDS, 16B per lane; lds dest is wave-uniform base + lane*16
__device__ __forceinline__ void gld16(const void* g, void* l) {
  __builtin_amdgcn_global_load_lds(
      (const __attribute__((address_space(1))) unsigned*)g,
      (__attribute__((address_space(3))) unsigned*)l, 16, 0, 0);
}

// ---- prep: bf16 convert + zero accumulators + class table + tile lists -----
__global__ __launch_bounds__(256) void prep_k(
    const float* __restrict__ f1, const float* __restrict__ f2,
    ushort_t* __restrict__ bf,
    float* __restrict__ neg_sum, unsigned* __restrict__ neg_max,
    float* __restrict__ sumS, float* __restrict__ corr,
    int* __restrict__ cnts, int* __restrict__ neg_list,
    int* __restrict__ pos_list, const int* __restrict__ ov)
{
  const int b = blockIdx.x, t = threadIdx.x;

  // f32 -> bf16 (concat feats1, feats2), 8 elems/thread
  {
    int i = b * 256 + t;
    size_t base = (size_t)i * 8;
    const size_t half = (size_t)N1T * FD;
    const float* sp = (base < half) ? (f1 + base) : (f2 + (base - half));
    float4 u0 = ((const float4*)sp)[0];
    float4 u1 = ((const float4*)sp)[1];
    short8 o;
    o[0] = (short)f2bf(u0.x); o[1] = (short)f2bf(u0.y);
    o[2] = (short)f2bf(u0.z); o[3] = (short)f2bf(u0.w);
    o[4] = (short)f2bf(u1.x); o[5] = (short)f2bf(u1.y);
    o[6] = (short)f2bf(u1.z); o[7] = (short)f2bf(u1.w);
    *(short8*)(bf + base) = o;
  }

  if (b >= 1 && b <= 16) {             // zero per-row accumulators
    int i = (b - 1) * 256 + t;
    neg_sum[i] = 0.f;
    neg_max[i] = 0u;                    // 0u < enc_ord(any float)
  }

  if (b == 0) {                         // parallel tile-list build
    __shared__ int c[16];
    if (t == 0) {
      sumS[0] = 0.f; corr[0] = 0.f;
      cnts[0] = 0; cnts[1] = 0; cnts[2] = 0;   // cnts[2] = done counter
      int excl = 0;
      for (int g = 0; g < KGRP; g++) c[g] = g;
      for (int g = 0; g < KGRP; g++) {
        if (ov[g]) c[KGRP + g] = g;
        else       { c[KGRP + g] = KGRP + excl; excl++; }
      }
    }
    __syncthreads();
    for (int p = t; p < 1024; p += 256) {
      int bi = p >> 5, bj = p & 31;
      if (bj < bi) continue;
      if (c[bi >> 1] == c[bj >> 1]) {
        int k = atomicAdd(&cnts[1], 1); pos_list[k] = (bi << 5) | bj;
      } else {
        int k = atomicAdd(&cnts[0], 1); neg_list[k] = (bi << 5) | bj;
      }
    }
  }
}

// ---- gram pass over all 528 upper-triangle tiles ---------------------------
// Barrier-free: wave-private LDS double buffer, per-wave counted vmcnt.
__global__ __launch_bounds__(256, 2) void gram_k(
    const ushort_t* __restrict__ bf, const int* __restrict__ cnts,
    const int* __restrict__ neg_list, const int* __restrict__ pos_list,
    float* __restrict__ neg_sum, unsigned* __restrict__ neg_max,
    float* __restrict__ pos_dots)
{
  __shared__ char lds[4 * 16384];      // per wave: 16 KB (2 bufs x (A4K|B4K))

  const int nn = cnts[0];
  const int b  = blockIdx.x;
  const bool isneg = (b < nn);
  const int pr = isneg ? neg_list[b] : pos_list[b - nn];
  const int bi = pr >> 5, bj = pr & 31;
  const int brow = bi << 7, bcol = bj << 7;

  const int t    = threadIdx.x;
  const int lane = t & 63, wave = t >> 6;
  const int wrow = (wave >> 1) << 6, wcol = (wave & 1) << 6;
  const int fr   = lane & 15, fh = lane >> 4;

  char* myLds = lds + wave * 16384;    // wave-private region

  // staging source: 16 rows/instr, lane -> row (lane>>2), chunk XOR-swizzled
  const int rq  = lane >> 2;
  const int csw = ((lane & 3) ^ ((lane >> 3) & 3)) << 3;  // elems
  const ushort_t* gA = bf + (size_t)(brow + wrow + rq) * FD + csw;
  const ushort_t* gB = bf + (size_t)(bcol + wcol + rq) * FD + csw;

  // fragment read byte offsets (same XOR on the read side)
  const int fx = ((fh ^ ((fr >> 1) & 3)) << 4);
  int offA[4], offB[4];
#pragma unroll
  for (int m = 0; m < 4; m++) offA[m] = (((m << 4) + fr) << 6) + fx;
#pragma unroll
  for (int n = 0; n < 4; n++) offB[n] = 4096 + (((n << 4) + fr) << 6) + fx;

  f32x4 acc[4][4];
#pragma unroll
  for (int m = 0; m < 4; m++)
#pragma unroll
    for (int n = 0; n < 4; n++)
      acc[m][n] = (f32x4){0.f, 0.f, 0.f, 0.f};

  // one stage = this wave's A-half (4KB) + B-half (4KB) for K-slice s
  auto stageW = [&](int s) {
    char* dst = myLds + ((s & 1) << 13);
    const ushort_t* a = gA + (s << 5);
    const ushort_t* p = gB + (s << 5);
    gld16(a,         dst);             // rows  0..15
    gld16(a +  8192, dst + 1024);      // rows 16..31  (16*FD elems)
    gld16(a + 16384, dst + 2048);      // rows 32..47
    gld16(a + 24576, dst + 3072);      // rows 48..63
    gld16(p,         dst + 4096);
    gld16(p +  8192, dst + 5120);
    gld16(p + 16384, dst + 6144);
    gld16(p + 24576, dst + 7168);
  };

  stageW(0);                            // 8 loads in flight

#pragma unroll
  for (int s = 0; s < 16; s++) {
    if (s + 1 < 16) stageW(s + 1);      // issue next stage (other buffer)
    // wait for stage(s)'s 8 loads (oldest); stage(s+1)'s 8 stay in flight
    if (s + 1 < 16) asm volatile("s_waitcnt vmcnt(8)" ::: "memory");
    else            asm volatile("s_waitcnt vmcnt(0)" ::: "memory");

    char* base = myLds + ((s & 1) << 13);
    short8 a[4], bb[4];
#pragma unroll
    for (int m = 0; m < 4; m++) a[m]  = *(const short8*)(base + offA[m]);
#pragma unroll
    for (int n = 0; n < 4; n++) bb[n] = *(const short8*)(base + offB[n]);

#pragma unroll
    for (int m = 0; m < 4; m++)
#pragma unroll
      for (int n = 0; n < 4; n++)
        acc[m][n] = __builtin_amdgcn_mfma_f32_16x16x32_bf16(a[m], bb[n], acc[m][n], 0, 0, 0);
  }

  const int rbase = brow + wrow + (fh << 2);
  const int cbase = bcol + wcol + fr;

  if (isneg) {
    // single-exp epilogue: row sums/maxes + column sums/maxes in one sweep
    float colS[4] = {0.f, 0.f, 0.f, 0.f};
    float colM[4] = {-3.0e38f, -3.0e38f, -3.0e38f, -3.0e38f};
#pragma unroll
    for (int m = 0; m < 4; m++) {
#pragma unroll
      for (int j = 0; j < 4; j++) {
        float s = 0.f, mx = -3.0e38f;
#pragma unroll
        for (int n = 0; n < 4; n++) {
          float d = acc[m][n][j];
          float e = __expf(d * TEMPW);
          s += e; mx = fmaxf(mx, d);
          colS[n] += e; colM[n] = fmaxf(colM[n], d);
        }
#pragma unroll
        for (int o = 1; o < 16; o <<= 1) {
          s  += __shfl_xor(s, o, 64);
          mx  = fmaxf(mx, __shfl_xor(mx, o, 64));
        }
        if (fr == 0) {
          int r = rbase + (m << 4) + j;
          atomicAdd(&neg_sum[r], s);
          atomicMax(&neg_max[r], enc_ord(mx));
        }
      }
    }
#pragma unroll
    for (int n = 0; n < 4; n++) {
      float s = colS[n], mx = colM[n];
      s += __shfl_xor(s, 16, 64); mx = fmaxf(mx, __shfl_xor(mx, 16, 64));
      s += __shfl_xor(s, 32, 64); mx = fmaxf(mx, __shfl_xor(mx, 32, 64));
      if (fh == 0) {
        int c = cbase + (n << 4);
        atomicAdd(&neg_sum[c], s);
        atomicMax(&neg_max[c], enc_ord(mx));
      }
    }
  } else {
    // pos tile: dump dots to scratch (compared after neg_max is final)
    float* basep = pos_dots + (size_t)(b - nn) * 16384;
#pragma unroll
    for (int m = 0; m < 4; m++)
#pragma unroll
      for (int n = 0; n < 4; n++)
        *(f32x4*)(basep + (((m << 2) + n) << 10) + (t << 2)) = acc[m][n];
  }
}

// ---- fused pos-compare + finalize (last pos block runs the finalize) -------
__global__ __launch_bounds__(256) void pos_fin_k(
    const float* __restrict__ pos_dots, const int* __restrict__ cnts,
    const int* __restrict__ pos_list, const unsigned* __restrict__ neg_max,
    const float* __restrict__ neg_sum, const int* __restrict__ ov,
    float* __restrict__ sumS, float* __restrict__ corr,
    int* __restrict__ done, float* __restrict__ out)
{
  const int np = cnts[1];
  const int p  = blockIdx.x;
  const int t  = threadIdx.x, lane = t & 63, wave = t >> 6;

  __shared__ float wsum[4];
  __shared__ int   wcnt[4];
  __shared__ int   amLast;

  if (p < np) {
    const int pr = pos_list[p];
    const int bi = pr >> 5, bj = pr & 31;
    const int wrow = (wave >> 1) << 6, wcol = (wave & 1) << 6;
    const int fr = lane & 15, fh = lane >> 4;
    const int rbase = (bi << 7) + wrow + (fh << 2);
    const int cbase = (bj << 7) + wcol + fr;
    const float cw = ((bi < 16) == (bj < 16)) ? 1.0f : 0.5f;
    const float* basep = pos_dots + (size_t)p * 16384;

    float ssum = 0.f;
    int cc = 0;
    if (bi == bj) {
#pragma unroll
      for (int m = 0; m < 4; m++)
#pragma unroll
        for (int n = 0; n < 4; n++) {
          f32x4 v = *(const f32x4*)(basep + (((m << 2) + n) << 10) + (t << 2));
          int c = cbase + (n << 4);
#pragma unroll
          for (int j = 0; j < 4; j++) {
            int r = rbase + (m << 4) + j;
            if (r != c) {
              float d = v[j];
              ssum += d;
              cc += (d > dec_ord(neg_max[r])) ? 1 : 0;
            }
          }
        }
    } else {
      float nmr[4][4], nmc[4];
#pragma unroll
      for (int m = 0; m < 4; m++)
#pragma unroll
        for (int j = 0; j < 4; j++) nmr[m][j] = dec_ord(neg_max[rbase + (m << 4) + j]);
#pragma unroll
      for (int n = 0; n < 4; n++) nmc[n] = dec_ord(neg_max[cbase + (n << 4)]);
#pragma unroll
      for (int m = 0; m < 4; m++)
#pragma unroll
        for (int n = 0; n < 4; n++) {
          f32x4 v = *(const f32x4*)(basep + (((m << 2) + n) << 10) + (t << 2));
#pragma unroll
          for (int j = 0; j < 4; j++) {
            float d = v[j];
            ssum += d;
            cc += ((d > nmr[m][j]) ? 1 : 0) + ((d > nmc[n]) ? 1 : 0);
          }
        }
      ssum *= 2.0f;   // both orientations
    }
    ssum *= cw;

#pragma unroll
    for (int o = 1; o < 64; o <<= 1) {
      ssum += __shfl_xor(ssum, o, 64);
      cc   += __shfl_xor(cc, o, 64);
    }
    if (lane == 0) { wsum[wave] = ssum; wcnt[wave] = cc; }
    __syncthreads();
    if (t == 0) {
      float S2 = 0.f; int C2 = 0;
      for (int w = 0; w < 4; w++) { S2 += wsum[w]; C2 += wcnt[w]; }
      atomicAdd(sumS, S2);
      atomicAdd(corr, (float)C2);
    }
  }

  // completion detection (block-uniform broadcast via shared)
  if (t == 0) {
    int my = -1;
    if (p < np) { __threadfence(); my = atomicAdd(done, 1); }
    amLast = (my == np - 1) ? 1 : 0;
  }
  __syncthreads();
  if (!amLast) return;
  __threadfence();

  // finalize: loss = (sum_r W_r*log(neg_sum_r) - TEMP*sumS) / total_pos
  float aa = 0.f;
  for (int r = t; r < NT; r += 256) {
    int g = r >> 8;                     // 256-row group, 0..15
    float W = ov[g & 7] ? 383.f : 255.f;
    aa += W * __logf(neg_sum[r]);
  }
#pragma unroll
  for (int o = 1; o < 64; o <<= 1) aa += __shfl_xor(aa, o, 64);
  if (lane == 0) wsum[wave] = aa;
  __syncthreads();
  if (t == 0) {
    float sw = wsum[0] + wsum[1] + wsum[2] + wsum[3];
    float S = atomicAdd(sumS, 0.f);     // coherent read past L1
    float C = atomicAdd(corr, 0.f);
    float tp = 0.f;
    for (int g = 0; g < 16; g++) tp += 256.f * (255.f + 256.f * (ov[g & 7] ? 1.f : 0.f));
    out[0] = C / tp;
    out[1] = (sw - TEMPW * S) / tp;
  }
}

// ---- launch ----------------------------------------------------------------

extern "C" void kernel_launch(void* const* d_in, const int* in_sizes, int n_in,
                              void* d_out, int out_size, void* d_ws, size_t ws_size,
                              hipStream_t stream)
{
  const float* f1 = (const float*)d_in[0];
  const float* f2 = (const float*)d_in[1];
  const int*   ov = (const int*)d_in[2];

  char* ws = (char*)d_ws;
  ushort_t* bf       = (ushort_t*)ws;                                    // 4 MB
  float*    neg_sum  = (float*)(ws + (size_t)(4 << 20));                 // 16 KB
  unsigned* neg_max  = (unsigned*)(ws + (size_t)(4 << 20) + (16 << 10)); // 16 KB
  float*    sumS     = (float*)(ws + (size_t)(4 << 20) + (32 << 10));
  float*    corr     = sumS + 1;
  int*      cnts     = (int*)(sumS + 2);                                 // 3 ints
  int*      done     = cnts + 2;
  int*      neg_list = (int*)(ws + (size_t)(4 << 20) + (36 << 10));      // <=480
  int*      pos_list = (int*)(ws + (size_t)(4 << 20) + (40 << 10));      // <=80
  float*    pos_dots = (float*)(ws + (size_t)(4 << 20) + (64 << 10));    // 5.25 MB
  float*    out      = (float*)d_out;

  hipLaunchKernelGGL(prep_k, dim3(1024), dim3(256), 0, stream,
                     f1, f2, bf, neg_sum, neg_max, sumS, corr, cnts,
                     neg_list, pos_list, ov);
  hipLaunchKernelGGL(gram_k, dim3(528), dim3(256), 0, stream,
                     bf, cnts, neg_list, pos_list, neg_sum, neg_max, pos_dots);
  hipLaunchKernelGGL(pos_fin_k, dim3(80), dim3(256), 0, stream,
                     pos_dots, cnts, pos_list, neg_max, neg_sum, ov,
                     sumS, corr, done, out);
}